// Round 1
// baseline (104714.868 us; speedup 1.0000x reference)
//
#include <hip/hip_runtime.h>
#include <math.h>

#define BATCH 128
#define LEN   64000
#define FS    256
#define STEPS 200
#define NFILT 64
#define HID   512
#define HID2  512
#define NOUT  10
#define NF    320        // number of frames
#define G4    2048       // 4*HID2

// ---------------------------------------------------------------------------
// Frontend: one block per (b, f) row.
// frame -> interval linear (256x258) -> interval square -> interval linear
// (258x64, +1e-10) -> log -> interval linear (64x512, +bias) -> relu
// Writes rl/ru to ws with layout [t][b][512].
// ---------------------------------------------------------------------------
__global__ __launch_bounds__(256) void frontend_kernel(
    const float* __restrict__ lb, const float* __restrict__ ub,
    const float* __restrict__ mtx1, const float* __restrict__ mtx2,
    const float* __restrict__ lin1_w, const float* __restrict__ lin1_b,
    float* __restrict__ rl_ws, float* __restrict__ ru_ws)
{
    const int bid = blockIdx.x;
    const int f = bid % NF;
    const int b = bid / NF;
    const int tid = threadIdx.x;

    __shared__ float sc[FS], sr[FS];
    __shared__ float s2c[FS + 2], s2r[FS + 2];
    __shared__ float s3c[NFILT], s3r[NFILT];

    // load frame (center/radius form); positions >= LEN are the zero pad
    {
        const int pos = f * STEPS + tid;
        float l = 0.f, u = 0.f;
        if (pos < LEN) {
            l = lb[(size_t)b * LEN + pos];
            u = ub[(size_t)b * LEN + pos];
        }
        sc[tid] = 0.5f * (l + u);
        sr[tid] = 0.5f * (u - l);
    }
    __syncthreads();

    // stage 1: 258 outputs, then interval square
    for (int j = tid; j < FS + 2; j += 256) {
        float oc = 0.f, orr = 0.f;
        for (int i = 0; i < FS; ++i) {
            const float w = mtx1[i * (FS + 2) + j];
            oc  = fmaf(sc[i], w, oc);
            orr = fmaf(sr[i], fabsf(w), orr);
        }
        const float l1l = oc - orr, l1u = oc + orr;
        const float a = l1l * l1l, bb = l1u * l1u;
        const float squ = fmaxf(a, bb);
        const float sql = (l1l <= 0.f && l1u >= 0.f) ? 0.f : fminf(a, bb);
        s2c[j] = 0.5f * (sql + squ);
        s2r[j] = 0.5f * (squ - sql);
    }
    __syncthreads();

    // stage 2: 64 outputs (+1e-10 bias), then log
    if (tid < NFILT) {
        const int j = tid;
        float oc = 1e-10f, orr = 0.f;
        for (int i = 0; i < FS + 2; ++i) {
            const float w = mtx2[i * NFILT + j];
            oc  = fmaf(s2c[i], w, oc);
            orr = fmaf(s2r[i], fabsf(w), orr);
        }
        const float lgl = logf(oc - orr);
        const float lgu = logf(oc + orr);
        s3c[j] = 0.5f * (lgl + lgu);
        s3r[j] = 0.5f * (lgu - lgl);
    }
    __syncthreads();

    // stage 3: 512 outputs (+bias), relu, write out
    for (int j = tid; j < HID; j += 256) {
        float oc = lin1_b[j], orr = 0.f;
        for (int i = 0; i < NFILT; ++i) {
            const float w = lin1_w[i * HID + j];
            oc  = fmaf(s3c[i], w, oc);
            orr = fmaf(s3r[i], fabsf(w), orr);
        }
        const float n1l = oc - orr, n1u = oc + orr;
        const size_t o = ((size_t)f * BATCH + b) * HID + j;
        rl_ws[o] = fmaxf(n1l, 0.f);
        ru_ws[o] = fmaxf(n1u, 0.f);
    }
}

// ---------------------------------------------------------------------------
// Gates GEMM: gl/gu[b][n] = (cx@Wx + ch@Wh) -/+ (rx@|Wx| + rh@|Wh|) + bias[n]
// A is built on the fly from (Xl,Xu) for k<512 and (Hl,Hu) for k>=512.
// M=128, N=2048, K=1024.  Tile: 32(M) x 64(N), K-tile 32, 256 threads,
// 8 (oc,orr) accumulator pairs per thread.
// ---------------------------------------------------------------------------
#define BM 32
#define BN 64
#define BK 32

__global__ __launch_bounds__(256) void gates_gemm_kernel(
    const float* __restrict__ Xl, const float* __restrict__ Xu,
    const float* __restrict__ Hl, const float* __restrict__ Hu,
    const float* __restrict__ Wx, const float* __restrict__ Wh,
    const float* __restrict__ bias,
    float* __restrict__ gl_out, float* __restrict__ gu_out)
{
    const int tid = threadIdx.x;
    const int m0 = blockIdx.y * BM;
    const int n0 = blockIdx.x * BN;

    __shared__ float Ac[BM][BK], Ar[BM][BK];
    __shared__ float Bs[BK][BN];

    float oc[8], orr[8];
#pragma unroll
    for (int i = 0; i < 8; ++i) { oc[i] = 0.f; orr[i] = 0.f; }

    const int nn = tid % BN;   // 0..63 (lane within wave)
    const int mg = tid / BN;   // 0..3

    const int ak = tid % BK;   // A-tile load coords
    const int am = tid / BK;   // 0..7
    const int bn = tid % BN;   // B-tile load coords
    const int bk = tid / BN;   // 0..3

    for (int k0 = 0; k0 < HID + HID2; k0 += BK) {
        // A tile (center & radius), 32x32
#pragma unroll
        for (int p = 0; p < BM; p += 8) {
            const int m = am + p;
            const int k = k0 + ak;
            float lo, hi;
            if (k < HID) {
                lo = Xl[(size_t)(m0 + m) * HID + k];
                hi = Xu[(size_t)(m0 + m) * HID + k];
            } else {
                lo = Hl[(size_t)(m0 + m) * HID2 + (k - HID)];
                hi = Hu[(size_t)(m0 + m) * HID2 + (k - HID)];
            }
            Ac[m][ak] = 0.5f * (lo + hi);
            Ar[m][ak] = 0.5f * (hi - lo);
        }
        // B tile, 32x64
#pragma unroll
        for (int p = 0; p < BK; p += 4) {
            const int k = k0 + bk + p;
            const float w = (k < HID) ? Wx[(size_t)k * G4 + n0 + bn]
                                      : Wh[(size_t)(k - HID) * G4 + n0 + bn];
            Bs[bk + p][bn] = w;
        }
        __syncthreads();

#pragma unroll
        for (int kk = 0; kk < BK; ++kk) {
            const float w = Bs[kk][nn];
            const float aw = fabsf(w);
#pragma unroll
            for (int i = 0; i < 8; ++i) {
                const int m = mg + 4 * i;
                oc[i]  = fmaf(Ac[m][kk], w,  oc[i]);
                orr[i] = fmaf(Ar[m][kk], aw, orr[i]);
            }
        }
        __syncthreads();
    }

    const float bsv = bias[n0 + nn];
#pragma unroll
    for (int i = 0; i < 8; ++i) {
        const int m = mg + 4 * i;
        const size_t o = (size_t)(m0 + m) * G4 + n0 + nn;
        gl_out[o] = oc[i] - orr[i] + bsv;
        gu_out[o] = oc[i] + orr[i] + bsv;
    }
}

// ---------------------------------------------------------------------------
// Cell elementwise update (in-place on h,c buffers)
// ---------------------------------------------------------------------------
__device__ __forceinline__ float sigmoidf_(float x) {
    return 1.f / (1.f + expf(-x));
}
__device__ __forceinline__ void imulf_(float al, float au, float bl, float bu,
                                       float& lo, float& hi) {
    const float p1 = al * bl, p2 = al * bu, p3 = au * bl, p4 = au * bu;
    lo = fminf(fminf(p1, p2), fminf(p3, p4));
    hi = fmaxf(fmaxf(p1, p2), fmaxf(p3, p4));
}

__global__ __launch_bounds__(256) void cell_kernel(
    const float* __restrict__ gl, const float* __restrict__ gu,
    float* __restrict__ hl, float* __restrict__ hu,
    float* __restrict__ cl, float* __restrict__ cu)
{
    const int idx = blockIdx.x * 256 + threadIdx.x;   // 0 .. 128*512-1
    const int b = idx / HID2;
    const int j = idx % HID2;
    const size_t base = (size_t)b * G4;

    float il = sigmoidf_(gl[base + j]);
    float iu = sigmoidf_(gu[base + j]);
    float fl = sigmoidf_(gl[base + HID2 + j]);
    float fu = sigmoidf_(gu[base + HID2 + j]);
    float ggl = tanhf(gl[base + 2 * HID2 + j]);
    float ggu = tanhf(gu[base + 2 * HID2 + j]);
    float ol = sigmoidf_(gl[base + 3 * HID2 + j]);
    float ou = sigmoidf_(gu[base + 3 * HID2 + j]);

    const float cl0 = cl[idx], cu0 = cu[idx];
    float fcl, fcu, igl, igu;
    imulf_(fl, fu, cl0, cu0, fcl, fcu);
    imulf_(il, iu, ggl, ggu, igl, igu);
    const float ncl = fcl + igl, ncu = fcu + igu;
    cl[idx] = ncl; cu[idx] = ncu;

    float nhl, nhu;
    imulf_(ol, ou, tanhf(ncl), tanhf(ncu), nhl, nhu);
    hl[idx] = nhl; hu[idx] = nhu;
}

// ---------------------------------------------------------------------------
// Final 512 -> 10 interval linear; out = [ol (128x10), ou (128x10)]
// ---------------------------------------------------------------------------
__global__ __launch_bounds__(64) void final_kernel(
    const float* __restrict__ h1l, const float* __restrict__ h1u,
    const float* __restrict__ w, const float* __restrict__ bias,
    float* __restrict__ out)
{
    const int b = blockIdx.x;
    const int j = threadIdx.x;
    if (j < NOUT) {
        float oc = bias[j], orr = 0.f;
        for (int i = 0; i < HID2; ++i) {
            const float lo = h1l[(size_t)b * HID2 + i];
            const float hi = h1u[(size_t)b * HID2 + i];
            const float wv = w[i * NOUT + j];
            oc  = fmaf(0.5f * (lo + hi), wv, oc);
            orr = fmaf(0.5f * (hi - lo), fabsf(wv), orr);
        }
        out[b * NOUT + j] = oc - orr;
        out[BATCH * NOUT + b * NOUT + j] = oc + orr;
    }
}

// ---------------------------------------------------------------------------
extern "C" void kernel_launch(void* const* d_in, const int* in_sizes, int n_in,
                              void* d_out, int out_size, void* d_ws, size_t ws_size,
                              hipStream_t stream)
{
    const float* input_lb = (const float*)d_in[0];
    const float* input_ub = (const float*)d_in[1];
    const float* mtx1     = (const float*)d_in[2];
    const float* mtx2     = (const float*)d_in[3];
    const float* lin1_w   = (const float*)d_in[4];
    const float* lin1_b   = (const float*)d_in[5];
    const float* w_ih0    = (const float*)d_in[6];
    const float* w_hh0    = (const float*)d_in[7];
    const float* b0       = (const float*)d_in[8];
    const float* w_ih1    = (const float*)d_in[9];
    const float* w_hh1    = (const float*)d_in[10];
    const float* b1       = (const float*)d_in[11];
    const float* lin2_w   = (const float*)d_in[12];
    const float* lin2_b   = (const float*)d_in[13];
    float* out = (float*)d_out;

    char* ws = (char*)d_ws;
    size_t off = 0;
    float* rl_ws = (float*)(ws + off); off += (size_t)NF * BATCH * HID * 4;
    float* ru_ws = (float*)(ws + off); off += (size_t)NF * BATCH * HID * 4;
    float* states = (float*)(ws + off); off += (size_t)8 * BATCH * HID2 * 4;
    float* gl_ws = (float*)(ws + off); off += (size_t)BATCH * G4 * 4;
    float* gu_ws = (float*)(ws + off); off += (size_t)BATCH * G4 * 4;

    float* h0l = states + 0 * BATCH * HID2;
    float* h0u = states + 1 * BATCH * HID2;
    float* c0l = states + 2 * BATCH * HID2;
    float* c0u = states + 3 * BATCH * HID2;
    float* h1l = states + 4 * BATCH * HID2;
    float* h1u = states + 5 * BATCH * HID2;
    float* c1l = states + 6 * BATCH * HID2;
    float* c1u = states + 7 * BATCH * HID2;

    // zero the LSTM state
    hipMemsetAsync(states, 0, (size_t)8 * BATCH * HID2 * 4, stream);

    // frontend: 40960 independent rows
    frontend_kernel<<<BATCH * NF, 256, 0, stream>>>(
        input_lb, input_ub, mtx1, mtx2, lin1_w, lin1_b, rl_ws, ru_ws);

    // sequential LSTM
    const dim3 ggrid(G4 / BN, BATCH / BM);   // 32 x 4
    for (int t = 0; t < NF; ++t) {
        const float* xl = rl_ws + (size_t)t * BATCH * HID;
        const float* xu = ru_ws + (size_t)t * BATCH * HID;
        gates_gemm_kernel<<<ggrid, 256, 0, stream>>>(
            xl, xu, h0l, h0u, w_ih0, w_hh0, b0, gl_ws, gu_ws);
        cell_kernel<<<(BATCH * HID2) / 256, 256, 0, stream>>>(
            gl_ws, gu_ws, h0l, h0u, c0l, c0u);
        gates_gemm_kernel<<<ggrid, 256, 0, stream>>>(
            h0l, h0u, h1l, h1u, w_ih1, w_hh1, b1, gl_ws, gu_ws);
        cell_kernel<<<(BATCH * HID2) / 256, 256, 0, stream>>>(
            gl_ws, gu_ws, h1l, h1u, c1l, c1u);
    }

    final_kernel<<<BATCH, 64, 0, stream>>>(h1l, h1u, lin2_w, lin2_b, out);
}

// Round 2
// 16536.137 us; speedup vs baseline: 6.3325x; 6.3325x over previous
//
#include <hip/hip_runtime.h>
#include <hip/hip_bf16.h>
#include <math.h>

#define BATCH 128
#define LEN   64000
#define FS    256
#define STEPS 200
#define NFILT 64
#define HID   512
#define HID2  512
#define NOUT  10
#define NF    320        // number of frames
#define G4    2048       // 4*HID2
#define KTOT  1024       // HID + HID2

typedef __bf16  bf16x8 __attribute__((ext_vector_type(8)));
typedef float   f32x4  __attribute__((ext_vector_type(4)));
typedef __hip_bfloat16 hbf;

// ---------------------------------------------------------------------------
// Frontend: one block per (b, f) row. fp32 math, writes bf16 center/radius
// with layout [t][b][512].
// ---------------------------------------------------------------------------
__global__ __launch_bounds__(256) void frontend_kernel(
    const float* __restrict__ lb, const float* __restrict__ ub,
    const float* __restrict__ mtx1, const float* __restrict__ mtx2,
    const float* __restrict__ lin1_w, const float* __restrict__ lin1_b,
    hbf* __restrict__ Xc, hbf* __restrict__ Xr)
{
    const int bid = blockIdx.x;
    const int f = bid % NF;
    const int b = bid / NF;
    const int tid = threadIdx.x;

    __shared__ float sc[FS], sr[FS];
    __shared__ float s2c[FS + 2], s2r[FS + 2];
    __shared__ float s3c[NFILT], s3r[NFILT];

    {
        const int pos = f * STEPS + tid;
        float l = 0.f, u = 0.f;
        if (pos < LEN) {
            l = lb[(size_t)b * LEN + pos];
            u = ub[(size_t)b * LEN + pos];
        }
        sc[tid] = 0.5f * (l + u);
        sr[tid] = 0.5f * (u - l);
    }
    __syncthreads();

    for (int j = tid; j < FS + 2; j += 256) {
        float oc = 0.f, orr = 0.f;
        for (int i = 0; i < FS; ++i) {
            const float w = mtx1[i * (FS + 2) + j];
            oc  = fmaf(sc[i], w, oc);
            orr = fmaf(sr[i], fabsf(w), orr);
        }
        const float l1l = oc - orr, l1u = oc + orr;
        const float a = l1l * l1l, bb = l1u * l1u;
        const float squ = fmaxf(a, bb);
        const float sql = (l1l <= 0.f && l1u >= 0.f) ? 0.f : fminf(a, bb);
        s2c[j] = 0.5f * (sql + squ);
        s2r[j] = 0.5f * (squ - sql);
    }
    __syncthreads();

    if (tid < NFILT) {
        const int j = tid;
        float oc = 1e-10f, orr = 0.f;
        for (int i = 0; i < FS + 2; ++i) {
            const float w = mtx2[i * NFILT + j];
            oc  = fmaf(s2c[i], w, oc);
            orr = fmaf(s2r[i], fabsf(w), orr);
        }
        const float lgl = logf(oc - orr);
        const float lgu = logf(oc + orr);
        s3c[j] = 0.5f * (lgl + lgu);
        s3r[j] = 0.5f * (lgu - lgl);
    }
    __syncthreads();

    for (int j = tid; j < HID; j += 256) {
        float oc = lin1_b[j], orr = 0.f;
        for (int i = 0; i < NFILT; ++i) {
            const float w = lin1_w[i * HID + j];
            oc  = fmaf(s3c[i], w, oc);
            orr = fmaf(s3r[i], fabsf(w), orr);
        }
        const float n1l = oc - orr, n1u = oc + orr;
        const float rl = fmaxf(n1l, 0.f), ru = fmaxf(n1u, 0.f);
        const size_t o = ((size_t)f * BATCH + b) * HID + j;
        Xc[o] = __float2bfloat16(0.5f * (rl + ru));
        Xr[o] = __float2bfloat16(0.5f * (ru - rl));
    }
}

// ---------------------------------------------------------------------------
// Weight prep: build Wt[n=2048][k=1024] bf16 and |Wt| bf16, where rows
// k<512 come from w_ih[k][n] and k>=512 from w_hh[k-512][n].
// Tiled 32x32 transpose. grid (2048/32, 1024/32), 256 threads.
// ---------------------------------------------------------------------------
__global__ __launch_bounds__(256) void prep_weights_kernel(
    const float* __restrict__ wih, const float* __restrict__ whh,
    hbf* __restrict__ Wt, hbf* __restrict__ Wta)
{
    __shared__ float tile[32][33];
    const int n0 = blockIdx.x * 32;
    const int k0 = blockIdx.y * 32;
    const int tx = threadIdx.x & 31;
    const int ty = threadIdx.x >> 5;   // 0..7

    for (int r = ty; r < 32; r += 8) {
        const int k = k0 + r;
        const float* src = (k < HID) ? (wih + (size_t)k * G4)
                                     : (whh + (size_t)(k - HID) * G4);
        tile[r][tx] = src[n0 + tx];
    }
    __syncthreads();
    for (int r = ty; r < 32; r += 8) {
        const int n = n0 + r;
        const float w = tile[tx][r];
        const size_t o = (size_t)n * KTOT + k0 + tx;
        Wt[o]  = __float2bfloat16(w);
        Wta[o] = __float2bfloat16(fabsf(w));
    }
}

// ---------------------------------------------------------------------------
// Gates GEMM, bf16 MFMA 16x16x32, dual (center, radius) accumulate.
// D[m][n] = sum_k A[m][k] * Wt[n][k];  k<512 from X, k>=512 from H.
// One wave per block; tile 16(m) x 64(n); grid (2048/64, 128/16) = (32, 8).
// No LDS: A and B fragments are direct b128 global loads.
// ---------------------------------------------------------------------------
__global__ __launch_bounds__(64) void gates_gemm_mfma(
    const hbf* __restrict__ Xc, const hbf* __restrict__ Xr,
    const hbf* __restrict__ Hc, const hbf* __restrict__ Hr,
    const hbf* __restrict__ Wt, const hbf* __restrict__ Wta,
    const float* __restrict__ bias,
    float* __restrict__ gl, float* __restrict__ gu)
{
    const int lane = threadIdx.x;      // 0..63
    const int rc   = lane & 15;        // A-row / B-col within tile
    const int g    = lane >> 4;        // k-group (0..3)
    const int m0   = blockIdx.y * 16;
    const int n0   = blockIdx.x * 64;

    f32x4 accC[4] = {f32x4{0,0,0,0}, f32x4{0,0,0,0}, f32x4{0,0,0,0}, f32x4{0,0,0,0}};
    f32x4 accR[4] = {f32x4{0,0,0,0}, f32x4{0,0,0,0}, f32x4{0,0,0,0}, f32x4{0,0,0,0}};

    const hbf* wr[4];
    const hbf* war[4];
#pragma unroll
    for (int f = 0; f < 4; ++f) {
        const size_t o = (size_t)(n0 + f * 16 + rc) * KTOT + 8 * g;
        wr[f]  = Wt + o;
        war[f] = Wta + o;
    }
    const hbf* acx = Xc + (size_t)(m0 + rc) * HID + 8 * g;
    const hbf* arx = Xr + (size_t)(m0 + rc) * HID + 8 * g;
    const hbf* ach = Hc + (size_t)(m0 + rc) * HID2 + 8 * g;
    const hbf* arh = Hr + (size_t)(m0 + rc) * HID2 + 8 * g;

    // half 0: X against Wt[:, 0:512); half 1: H against Wt[:, 512:1024)
#pragma unroll 4
    for (int k0 = 0; k0 < HID; k0 += 32) {
        bf16x8 ac = *(const bf16x8*)(acx + k0);
        bf16x8 ar = *(const bf16x8*)(arx + k0);
#pragma unroll
        for (int f = 0; f < 4; ++f) {
            bf16x8 bc = *(const bf16x8*)(wr[f] + k0);
            bf16x8 ba = *(const bf16x8*)(war[f] + k0);
            accC[f] = __builtin_amdgcn_mfma_f32_16x16x32_bf16(ac, bc, accC[f], 0, 0, 0);
            accR[f] = __builtin_amdgcn_mfma_f32_16x16x32_bf16(ar, ba, accR[f], 0, 0, 0);
        }
    }
#pragma unroll 4
    for (int k0 = 0; k0 < HID2; k0 += 32) {
        bf16x8 ac = *(const bf16x8*)(ach + k0);
        bf16x8 ar = *(const bf16x8*)(arh + k0);
#pragma unroll
        for (int f = 0; f < 4; ++f) {
            bf16x8 bc = *(const bf16x8*)(wr[f] + HID + k0);
            bf16x8 ba = *(const bf16x8*)(war[f] + HID + k0);
            accC[f] = __builtin_amdgcn_mfma_f32_16x16x32_bf16(ac, bc, accC[f], 0, 0, 0);
            accR[f] = __builtin_amdgcn_mfma_f32_16x16x32_bf16(ar, ba, accR[f], 0, 0, 0);
        }
    }

    // epilogue: D col = lane&15, D row = 4*(lane>>4)+reg  [m89-verified]
#pragma unroll
    for (int f = 0; f < 4; ++f) {
        const int n = n0 + f * 16 + rc;
        const float bs = bias[n];
#pragma unroll
        for (int reg = 0; reg < 4; ++reg) {
            const int m = m0 + 4 * g + reg;
            const float c = accC[f][reg], r = accR[f][reg];
            const size_t o = (size_t)m * G4 + n;
            gl[o] = c - r + bs;
            gu[o] = c + r + bs;
        }
    }
}

// ---------------------------------------------------------------------------
// Cell elementwise update (in-place on c buffers). Emits bf16 h center/radius
// for the next GEMM and fp32 h bounds for the final layer.
// ---------------------------------------------------------------------------
__device__ __forceinline__ float sigmoidf_(float x) {
    return 1.f / (1.f + expf(-x));
}
__device__ __forceinline__ void imulf_(float al, float au, float bl, float bu,
                                       float& lo, float& hi) {
    const float p1 = al * bl, p2 = al * bu, p3 = au * bl, p4 = au * bu;
    lo = fminf(fminf(p1, p2), fminf(p3, p4));
    hi = fmaxf(fmaxf(p1, p2), fmaxf(p3, p4));
}

__global__ __launch_bounds__(256) void cell_kernel(
    const float* __restrict__ gl, const float* __restrict__ gu,
    float* __restrict__ cl, float* __restrict__ cu,
    hbf* __restrict__ Hc, hbf* __restrict__ Hr,
    float* __restrict__ hl, float* __restrict__ hu)
{
    const int idx = blockIdx.x * 256 + threadIdx.x;   // 0 .. 128*512-1
    const int b = idx / HID2;
    const int j = idx % HID2;
    const size_t base = (size_t)b * G4;

    float il = sigmoidf_(gl[base + j]);
    float iu = sigmoidf_(gu[base + j]);
    float fl = sigmoidf_(gl[base + HID2 + j]);
    float fu = sigmoidf_(gu[base + HID2 + j]);
    float ggl = tanhf(gl[base + 2 * HID2 + j]);
    float ggu = tanhf(gu[base + 2 * HID2 + j]);
    float ol = sigmoidf_(gl[base + 3 * HID2 + j]);
    float ou = sigmoidf_(gu[base + 3 * HID2 + j]);

    const float cl0 = cl[idx], cu0 = cu[idx];
    float fcl, fcu, igl, igu;
    imulf_(fl, fu, cl0, cu0, fcl, fcu);
    imulf_(il, iu, ggl, ggu, igl, igu);
    const float ncl = fcl + igl, ncu = fcu + igu;
    cl[idx] = ncl; cu[idx] = ncu;

    float nhl, nhu;
    imulf_(ol, ou, tanhf(ncl), tanhf(ncu), nhl, nhu);
    hl[idx] = nhl; hu[idx] = nhu;
    Hc[idx] = __float2bfloat16(0.5f * (nhl + nhu));
    Hr[idx] = __float2bfloat16(0.5f * (nhu - nhl));
}

// ---------------------------------------------------------------------------
// Final 512 -> 10 interval linear; out = [ol (128x10), ou (128x10)]
// ---------------------------------------------------------------------------
__global__ __launch_bounds__(64) void final_kernel(
    const float* __restrict__ h1l, const float* __restrict__ h1u,
    const float* __restrict__ w, const float* __restrict__ bias,
    float* __restrict__ out)
{
    const int b = blockIdx.x;
    const int j = threadIdx.x;
    if (j < NOUT) {
        float oc = bias[j], orr = 0.f;
        for (int i = 0; i < HID2; ++i) {
            const float lo = h1l[(size_t)b * HID2 + i];
            const float hi = h1u[(size_t)b * HID2 + i];
            const float wv = w[i * NOUT + j];
            oc  = fmaf(0.5f * (lo + hi), wv, oc);
            orr = fmaf(0.5f * (hi - lo), fabsf(wv), orr);
        }
        out[b * NOUT + j] = oc - orr;
        out[BATCH * NOUT + b * NOUT + j] = oc + orr;
    }
}

// ---------------------------------------------------------------------------
extern "C" void kernel_launch(void* const* d_in, const int* in_sizes, int n_in,
                              void* d_out, int out_size, void* d_ws, size_t ws_size,
                              hipStream_t stream)
{
    const float* input_lb = (const float*)d_in[0];
    const float* input_ub = (const float*)d_in[1];
    const float* mtx1     = (const float*)d_in[2];
    const float* mtx2     = (const float*)d_in[3];
    const float* lin1_w   = (const float*)d_in[4];
    const float* lin1_b   = (const float*)d_in[5];
    const float* w_ih0    = (const float*)d_in[6];
    const float* w_hh0    = (const float*)d_in[7];
    const float* b0       = (const float*)d_in[8];
    const float* w_ih1    = (const float*)d_in[9];
    const float* w_hh1    = (const float*)d_in[10];
    const float* b1       = (const float*)d_in[11];
    const float* lin2_w   = (const float*)d_in[12];
    const float* lin2_b   = (const float*)d_in[13];
    float* out = (float*)d_out;

    char* ws = (char*)d_ws;
    size_t off = 0;
    hbf* Xc = (hbf*)(ws + off); off += (size_t)NF * BATCH * HID * 2;
    hbf* Xr = (hbf*)(ws + off); off += (size_t)NF * BATCH * HID * 2;
    hbf* Wt0  = (hbf*)(ws + off); off += (size_t)G4 * KTOT * 2;
    hbf* Wt0a = (hbf*)(ws + off); off += (size_t)G4 * KTOT * 2;
    hbf* Wt1  = (hbf*)(ws + off); off += (size_t)G4 * KTOT * 2;
    hbf* Wt1a = (hbf*)(ws + off); off += (size_t)G4 * KTOT * 2;
    // zeroed state region (bf16 H then fp32 c): one memset covers it
    char* zero_base = ws + off;
    hbf* H0c = (hbf*)(ws + off); off += (size_t)BATCH * HID2 * 2;
    hbf* H0r = (hbf*)(ws + off); off += (size_t)BATCH * HID2 * 2;
    hbf* H1c = (hbf*)(ws + off); off += (size_t)BATCH * HID2 * 2;
    hbf* H1r = (hbf*)(ws + off); off += (size_t)BATCH * HID2 * 2;
    float* c0l = (float*)(ws + off); off += (size_t)BATCH * HID2 * 4;
    float* c0u = (float*)(ws + off); off += (size_t)BATCH * HID2 * 4;
    float* c1l = (float*)(ws + off); off += (size_t)BATCH * HID2 * 4;
    float* c1u = (float*)(ws + off); off += (size_t)BATCH * HID2 * 4;
    size_t zero_bytes = (size_t)(ws + off - zero_base);
    float* h0l = (float*)(ws + off); off += (size_t)BATCH * HID2 * 4;
    float* h0u = (float*)(ws + off); off += (size_t)BATCH * HID2 * 4;
    float* h1l = (float*)(ws + off); off += (size_t)BATCH * HID2 * 4;
    float* h1u = (float*)(ws + off); off += (size_t)BATCH * HID2 * 4;
    float* gl_ws = (float*)(ws + off); off += (size_t)BATCH * G4 * 4;
    float* gu_ws = (float*)(ws + off); off += (size_t)BATCH * G4 * 4;

    hipMemsetAsync(zero_base, 0, zero_bytes, stream);

    // weight prep (transpose + bf16 + abs)
    {
        const dim3 pgrid(G4 / 32, KTOT / 32);
        prep_weights_kernel<<<pgrid, 256, 0, stream>>>(w_ih0, w_hh0, Wt0, Wt0a);
        prep_weights_kernel<<<pgrid, 256, 0, stream>>>(w_ih1, w_hh1, Wt1, Wt1a);
    }

    // frontend: 40960 independent rows
    frontend_kernel<<<BATCH * NF, 256, 0, stream>>>(
        input_lb, input_ub, mtx1, mtx2, lin1_w, lin1_b, Xc, Xr);

    // sequential LSTM
    const dim3 ggrid(G4 / 64, BATCH / 16);   // (32, 8)
    for (int t = 0; t < NF; ++t) {
        const hbf* xc = Xc + (size_t)t * BATCH * HID;
        const hbf* xr = Xr + (size_t)t * BATCH * HID;
        gates_gemm_mfma<<<ggrid, 64, 0, stream>>>(
            xc, xr, H0c, H0r, Wt0, Wt0a, b0, gl_ws, gu_ws);
        cell_kernel<<<(BATCH * HID2) / 256, 256, 0, stream>>>(
            gl_ws, gu_ws, c0l, c0u, H0c, H0r, h0l, h0u);
        gates_gemm_mfma<<<ggrid, 64, 0, stream>>>(
            H0c, H0r, H1c, H1r, Wt1, Wt1a, b1, gl_ws, gu_ws);
        cell_kernel<<<(BATCH * HID2) / 256, 256, 0, stream>>>(
            gl_ws, gu_ws, c1l, c1u, H1c, H1r, h1l, h1u);
    }

    final_kernel<<<BATCH, 64, 0, stream>>>(h1l, h1u, lin2_w, lin2_b, out);
}

// Round 3
// 8383.406 us; speedup vs baseline: 12.4907x; 1.9725x over previous
//
#include <hip/hip_runtime.h>
#include <hip/hip_bf16.h>
#include <math.h>

#define BATCH 128
#define LEN   64000
#define FS    256
#define STEPS 200
#define NFILT 64
#define HID   512
#define HID2  512
#define NOUT  10
#define NF    320        // number of frames / timesteps
#define G4    2048       // 4*HID2
#define KTOT  1024       // HID + HID2
#define KH    512        // K half per wave

typedef __bf16  bf16x8 __attribute__((ext_vector_type(8)));
typedef float   f32x4  __attribute__((ext_vector_type(4)));
typedef __hip_bfloat16 hbf;

// ---------------------------------------------------------------------------
// Fast transcendentals (feed bf16 outputs; 1e-6 rel error is fine)
// ---------------------------------------------------------------------------
__device__ __forceinline__ float fsig(float x) {
    return 1.f / (1.f + __expf(-x));
}
__device__ __forceinline__ float ftanh(float x) {
    return 1.f - 2.f / (__expf(2.f * x) + 1.f);
}
__device__ __forceinline__ void imulf_(float al, float au, float bl, float bu,
                                       float& lo, float& hi) {
    const float p1 = al * bl, p2 = al * bu, p3 = au * bl, p4 = au * bu;
    lo = fminf(fminf(p1, p2), fminf(p3, p4));
    hi = fmaxf(fmaxf(p1, p2), fmaxf(p3, p4));
}

// ---------------------------------------------------------------------------
// Frontend: 8 (b,f)-rows per block, one wave per row (512 threads).
// fp32 math, writes bf16 center/radius with layout [t][b][512].
// ---------------------------------------------------------------------------
__global__ __launch_bounds__(512) void frontend_kernel(
    const float* __restrict__ lb, const float* __restrict__ ub,
    const float* __restrict__ mtx1, const float* __restrict__ mtx2,
    const float* __restrict__ lin1_w, const float* __restrict__ lin1_b,
    hbf* __restrict__ Xc, hbf* __restrict__ Xr)
{
    const int tid  = threadIdx.x;
    const int r    = tid >> 6;      // row within block (0..7)
    const int lane = tid & 63;
    const int rowid = blockIdx.x * 8 + r;   // = b*NF + f (NF%8==0, no b-crossing)
    const int f = rowid % NF;
    const int b = rowid / NF;

    __shared__ float sc[8][FS], sr[8][FS];
    __shared__ float s2c[8][FS + 2], s2r[8][FS + 2];
    __shared__ float s3c[8][NFILT], s3r[8][NFILT];

    for (int i = lane; i < FS; i += 64) {
        const int pos = f * STEPS + i;
        float l = 0.f, u = 0.f;
        if (pos < LEN) {
            l = lb[(size_t)b * LEN + pos];
            u = ub[(size_t)b * LEN + pos];
        }
        sc[r][i] = 0.5f * (l + u);
        sr[r][i] = 0.5f * (u - l);
    }
    __syncthreads();

    // stage 1: 258 outputs per row, then interval square
    for (int j = lane; j < FS + 2; j += 64) {
        float oc = 0.f, orr = 0.f;
#pragma unroll 4
        for (int i = 0; i < FS; ++i) {
            const float w = mtx1[i * (FS + 2) + j];
            oc  = fmaf(sc[r][i], w, oc);
            orr = fmaf(sr[r][i], fabsf(w), orr);
        }
        const float l1l = oc - orr, l1u = oc + orr;
        const float a = l1l * l1l, bb = l1u * l1u;
        const float squ = fmaxf(a, bb);
        const float sql = (l1l <= 0.f && l1u >= 0.f) ? 0.f : fminf(a, bb);
        s2c[r][j] = 0.5f * (sql + squ);
        s2r[r][j] = 0.5f * (squ - sql);
    }
    __syncthreads();

    // stage 2: 64 outputs per row (+1e-10), then log
    {
        const int j = lane;   // 0..63
        float oc = 1e-10f, orr = 0.f;
#pragma unroll 4
        for (int i = 0; i < FS + 2; ++i) {
            const float w = mtx2[i * NFILT + j];
            oc  = fmaf(s2c[r][i], w, oc);
            orr = fmaf(s2r[r][i], fabsf(w), orr);
        }
        const float lgl = logf(oc - orr);
        const float lgu = logf(oc + orr);
        s3c[r][j] = 0.5f * (lgl + lgu);
        s3r[r][j] = 0.5f * (lgu - lgl);
    }
    __syncthreads();

    // stage 3: 512 outputs per row (+bias), relu, write bf16 c/r
    for (int j = lane; j < HID; j += 64) {
        float oc = lin1_b[j], orr = 0.f;
#pragma unroll 4
        for (int i = 0; i < NFILT; ++i) {
            const float w = lin1_w[i * HID + j];
            oc  = fmaf(s3c[r][i], w, oc);
            orr = fmaf(s3r[r][i], fabsf(w), orr);
        }
        const float n1l = oc - orr, n1u = oc + orr;
        const float rl = fmaxf(n1l, 0.f), ru = fmaxf(n1u, 0.f);
        const size_t o = ((size_t)f * BATCH + b) * HID + j;
        Xc[o] = __float2bfloat16(0.5f * (rl + ru));
        Xr[o] = __float2bfloat16(0.5f * (ru - rl));
    }
}

// ---------------------------------------------------------------------------
// Weight prep: Wt[n=2048][k=1024] bf16 and |Wt| bf16; k<512 from w_ih,
// k>=512 from w_hh. Tiled 32x32 transpose.
// ---------------------------------------------------------------------------
__global__ __launch_bounds__(256) void prep_weights_kernel(
    const float* __restrict__ wih, const float* __restrict__ whh,
    hbf* __restrict__ Wt, hbf* __restrict__ Wta)
{
    __shared__ float tile[32][33];
    const int n0 = blockIdx.x * 32;
    const int k0 = blockIdx.y * 32;
    const int tx = threadIdx.x & 31;
    const int ty = threadIdx.x >> 5;   // 0..7

    for (int r = ty; r < 32; r += 8) {
        const int k = k0 + r;
        const float* src = (k < HID) ? (wih + (size_t)k * G4)
                                     : (whh + (size_t)(k - HID) * G4);
        tile[r][tx] = src[n0 + tx];
    }
    __syncthreads();
    for (int r = ty; r < 32; r += 8) {
        const int n = n0 + r;
        const float w = tile[tx][r];
        const size_t o = (size_t)n * KTOT + k0 + tx;
        Wt[o]  = __float2bfloat16(w);
        Wta[o] = __float2bfloat16(fabsf(w));
    }
}

// ---------------------------------------------------------------------------
// Fused gates-GEMM + LSTM cell.
// Block = 256 threads = 4 waves; wave w: op = w&1 (center/radius),
// ks = w>>1 (K half: 0 -> x-part, 1 -> h-part).
// Block tile: 16 batch rows (m0) x 16 hidden cols (j0) x all 4 gates.
// After MFMA, partial sums are reduced through LDS and the full cell
// update runs with one thread per (m, j) element.
// H is double-buffered by the caller (other blocks read old H during GEMM).
// ---------------------------------------------------------------------------
__global__ __launch_bounds__(256) void lstm_fused_kernel(
    const hbf* __restrict__ Xc, const hbf* __restrict__ Xr,   // x-part, stride HID
    const hbf* __restrict__ Hc, const hbf* __restrict__ Hr,   // h-part (old), stride HID2
    const hbf* __restrict__ Wt, const hbf* __restrict__ Wta,  // [2048][1024] bf16
    const float* __restrict__ bias,
    float* __restrict__ cl, float* __restrict__ cu,           // c state, in-place
    hbf* __restrict__ Hco, hbf* __restrict__ Hro,             // new h (bf16 c/r)
    float* __restrict__ hl, float* __restrict__ hu)           // optional fp32 h out
{
    const int tid  = threadIdx.x;
    const int w    = tid >> 6;      // wave 0..3
    const int lane = tid & 63;
    const int op   = w & 1;         // 0 = center, 1 = radius
    const int ks   = w >> 1;        // K half
    const int rc   = lane & 15;
    const int gk   = lane >> 4;     // k-group within fragment
    const int j0   = blockIdx.x * 16;
    const int m0   = blockIdx.y * 16;

    __shared__ float red[4][4][64][4];   // [wave][gate][lane][reg], 16 KB

    f32x4 acc[4] = {f32x4{0,0,0,0}, f32x4{0,0,0,0}, f32x4{0,0,0,0}, f32x4{0,0,0,0}};

    const hbf* Ab = ks ? (op ? Hr : Hc) : (op ? Xr : Xc);
    const hbf* Wb = op ? Wta : Wt;
    const hbf* aptr = Ab + (size_t)(m0 + rc) * HID + 8 * gk;
    const hbf* wp[4];
#pragma unroll
    for (int g = 0; g < 4; ++g)
        wp[g] = Wb + (size_t)(g * HID2 + j0 + rc) * KTOT + ks * KH + 8 * gk;

#pragma unroll
    for (int kk = 0; kk < KH; kk += 32) {
        const bf16x8 a = *(const bf16x8*)(aptr + kk);
#pragma unroll
        for (int g = 0; g < 4; ++g) {
            const bf16x8 bfrag = *(const bf16x8*)(wp[g] + kk);
            acc[g] = __builtin_amdgcn_mfma_f32_16x16x32_bf16(a, bfrag, acc[g], 0, 0, 0);
        }
    }

#pragma unroll
    for (int g = 0; g < 4; ++g)
        *((f32x4*)&red[w][g][lane][0]) = acc[g];
    __syncthreads();

    // ---- cell phase: one thread per (m, j) ----
    const int m  = tid >> 4;        // 0..15 batch row within tile
    const int j  = tid & 15;        // hidden col within tile
    const int ll = ((m >> 2) << 4) | j;   // lane that held D[m][j]
    const int rr = m & 3;                 // reg within that lane

    float gl[4], gu[4];
#pragma unroll
    for (int g = 0; g < 4; ++g) {
        const float C = red[0][g][ll][rr] + red[2][g][ll][rr];
        const float R = red[1][g][ll][rr] + red[3][g][ll][rr];
        const float bs = bias[g * HID2 + j0 + j];
        gl[g] = C - R + bs;
        gu[g] = C + R + bs;
    }

    const float il = fsig(gl[0]), iu = fsig(gu[0]);
    const float fl = fsig(gl[1]), fu = fsig(gu[1]);
    const float ggl = ftanh(gl[2]), ggu = ftanh(gu[2]);
    const float ol = fsig(gl[3]), ou = fsig(gu[3]);

    const int idx = (m0 + m) * HID2 + j0 + j;
    const float cl0 = cl[idx], cu0 = cu[idx];
    float fcl, fcu, igl, igu;
    imulf_(fl, fu, cl0, cu0, fcl, fcu);
    imulf_(il, iu, ggl, ggu, igl, igu);
    const float ncl = fcl + igl, ncu = fcu + igu;
    cl[idx] = ncl; cu[idx] = ncu;

    float nhl, nhu;
    imulf_(ol, ou, ftanh(ncl), ftanh(ncu), nhl, nhu);
    Hco[idx] = __float2bfloat16(0.5f * (nhl + nhu));
    Hro[idx] = __float2bfloat16(0.5f * (nhu - nhl));
    if (hl != nullptr) {
        hl[idx] = nhl;
        hu[idx] = nhu;
    }
}

// ---------------------------------------------------------------------------
// Final 512 -> 10 interval linear; out = [ol (128x10), ou (128x10)]
// ---------------------------------------------------------------------------
__global__ __launch_bounds__(64) void final_kernel(
    const float* __restrict__ h1l, const float* __restrict__ h1u,
    const float* __restrict__ w, const float* __restrict__ bias,
    float* __restrict__ out)
{
    const int b = blockIdx.x;
    const int j = threadIdx.x;
    if (j < NOUT) {
        float oc = bias[j], orr = 0.f;
        for (int i = 0; i < HID2; ++i) {
            const float lo = h1l[(size_t)b * HID2 + i];
            const float hi = h1u[(size_t)b * HID2 + i];
            const float wv = w[i * NOUT + j];
            oc  = fmaf(0.5f * (lo + hi), wv, oc);
            orr = fmaf(0.5f * (hi - lo), fabsf(wv), orr);
        }
        out[b * NOUT + j] = oc - orr;
        out[BATCH * NOUT + b * NOUT + j] = oc + orr;
    }
}

// ---------------------------------------------------------------------------
extern "C" void kernel_launch(void* const* d_in, const int* in_sizes, int n_in,
                              void* d_out, int out_size, void* d_ws, size_t ws_size,
                              hipStream_t stream)
{
    const float* input_lb = (const float*)d_in[0];
    const float* input_ub = (const float*)d_in[1];
    const float* mtx1     = (const float*)d_in[2];
    const float* mtx2     = (const float*)d_in[3];
    const float* lin1_w   = (const float*)d_in[4];
    const float* lin1_b   = (const float*)d_in[5];
    const float* w_ih0    = (const float*)d_in[6];
    const float* w_hh0    = (const float*)d_in[7];
    const float* b0       = (const float*)d_in[8];
    const float* w_ih1    = (const float*)d_in[9];
    const float* w_hh1    = (const float*)d_in[10];
    const float* b1       = (const float*)d_in[11];
    const float* lin2_w   = (const float*)d_in[12];
    const float* lin2_b   = (const float*)d_in[13];
    float* out = (float*)d_out;

    char* ws = (char*)d_ws;
    size_t off = 0;
    hbf* Xc = (hbf*)(ws + off); off += (size_t)NF * BATCH * HID * 2;
    hbf* Xr = (hbf*)(ws + off); off += (size_t)NF * BATCH * HID * 2;
    hbf* Wt0  = (hbf*)(ws + off); off += (size_t)G4 * KTOT * 2;
    hbf* Wt0a = (hbf*)(ws + off); off += (size_t)G4 * KTOT * 2;
    hbf* Wt1  = (hbf*)(ws + off); off += (size_t)G4 * KTOT * 2;
    hbf* Wt1a = (hbf*)(ws + off); off += (size_t)G4 * KTOT * 2;

    // zeroed state region: H double-buffers (bf16) + c (fp32)
    char* zero_base = ws + off;
    const size_t HSZ = (size_t)BATCH * HID2;   // elements
    hbf* H0c[2]; hbf* H0r[2]; hbf* H1c[2]; hbf* H1r[2];
    for (int i = 0; i < 2; ++i) {
        H0c[i] = (hbf*)(ws + off); off += HSZ * 2;
        H0r[i] = (hbf*)(ws + off); off += HSZ * 2;
        H1c[i] = (hbf*)(ws + off); off += HSZ * 2;
        H1r[i] = (hbf*)(ws + off); off += HSZ * 2;
    }
    float* c0l = (float*)(ws + off); off += HSZ * 4;
    float* c0u = (float*)(ws + off); off += HSZ * 4;
    float* c1l = (float*)(ws + off); off += HSZ * 4;
    float* c1u = (float*)(ws + off); off += HSZ * 4;
    const size_t zero_bytes = (size_t)((ws + off) - zero_base);
    float* h1l = (float*)(ws + off); off += HSZ * 4;
    float* h1u = (float*)(ws + off); off += HSZ * 4;

    hipMemsetAsync(zero_base, 0, zero_bytes, stream);

    // weight prep (transpose + bf16 + abs)
    {
        const dim3 pgrid(G4 / 32, KTOT / 32);
        prep_weights_kernel<<<pgrid, 256, 0, stream>>>(w_ih0, w_hh0, Wt0, Wt0a);
        prep_weights_kernel<<<pgrid, 256, 0, stream>>>(w_ih1, w_hh1, Wt1, Wt1a);
    }

    // frontend: 40960 rows, 8 per block
    frontend_kernel<<<(BATCH * NF) / 8, 512, 0, stream>>>(
        input_lb, input_ub, mtx1, mtx2, lin1_w, lin1_b, Xc, Xr);

    // sequential LSTM: 2 fused launches per step
    const dim3 ggrid(HID2 / 16, BATCH / 16);   // (32, 8)
    for (int t = 0; t < NF; ++t) {
        const int rd = t & 1, wr = (t + 1) & 1;
        const hbf* xc = Xc + (size_t)t * BATCH * HID;
        const hbf* xr = Xr + (size_t)t * BATCH * HID;
        lstm_fused_kernel<<<ggrid, 256, 0, stream>>>(
            xc, xr, H0c[rd], H0r[rd], Wt0, Wt0a, b0,
            c0l, c0u, H0c[wr], H0r[wr], nullptr, nullptr);
        const bool last = (t == NF - 1);
        lstm_fused_kernel<<<ggrid, 256, 0, stream>>>(
            H0c[wr], H0r[wr], H1c[rd], H1r[rd], Wt1, Wt1a, b1,
            c1l, c1u, H1c[wr], H1r[wr],
            last ? h1l : nullptr, last ? h1u : nullptr);
    }

    final_kernel<<<BATCH, 64, 0, stream>>>(h1l, h1u, lin2_w, lin2_b, out);
}